// Round 6
// baseline (91.473 us; speedup 1.0000x reference)
//
#include <hip/hip_runtime.h>

// Problem constants (from reference)
constexpr int Bn    = 262144;
constexpr int NNUM  = 64;
constexpr int FCAT  = 32;
constexpr int NCAT  = 8;
constexpr int NFEAT = NNUM + FCAT * NCAT;  // 320
constexpr int NPHEN = NNUM + FCAT;         // 96

// Native clang vector type (accepted by __builtin_nontemporal_load/store)
typedef float fx4 __attribute__((ext_vector_type(4)));

// tanh(x) given a = 2x:  tanh(x) = 1 - 2/(exp(2x)+1)
__device__ __forceinline__ float tanh_from_2x(float a) {
    float e = __expf(a);
    float r = __builtin_amdgcn_rcpf(e + 1.0f);
    return fmaf(-2.0f, r, 1.0f);
}

__global__ __launch_bounds__(256) void model_kernel(
    const float* __restrict__ num_x,   // (B, 64)
    const float* __restrict__ cat_x,   // (32, B, 8)
    const float* __restrict__ W,       // (2, 320)
    const float* __restrict__ M,       // (2, 96)
    float* __restrict__ out)           // (2, B)
{
    // Weights in LDS (uniform-address broadcast reads, conflict-free).
    // sW2 = 2*W so dot products feed exp(2x) directly.
    __shared__ float sW2[2 * NFEAT];
    __shared__ float sM[2 * NPHEN];
    const int tid = threadIdx.x;
    for (int i = tid; i < 2 * NFEAT; i += 256) sW2[i] = 2.0f * W[i];
    for (int i = tid; i < 2 * NPHEN; i += 256) sM[i] = M[i];

    const int b = blockIdx.x * 256 + tid;
    const float* cbase = cat_x + (size_t)b * NCAT;
    const size_t fstride = (size_t)Bn * NCAT;   // per-f stride (floats)

    // ---- prefetch cat group 0 (4 f's x 2 fx4) BEFORE num compute ----
    fx4 bufA[8], bufB[8];
    #pragma unroll
    for (int q = 0; q < 4; ++q) {
        const fx4* cx = reinterpret_cast<const fx4*>(cbase + (size_t)q * fstride);
        bufA[q * 2 + 0] = __builtin_nontemporal_load(cx);
        bufA[q * 2 + 1] = __builtin_nontemporal_load(cx + 1);
    }

    __syncthreads();

    float f0 = 0.0f, f1 = 0.0f;

    // ---- numerical features: 16 x fx4 per-thread row (nt streaming) ----
    const fx4* nx = reinterpret_cast<const fx4*>(num_x + (size_t)b * NNUM);
    #pragma unroll
    for (int i = 0; i < NNUM / 4; ++i) {
        fx4 v = __builtin_nontemporal_load(nx + i);
        #pragma unroll
        for (int j = 0; j < 4; ++j) {
            const int k = i * 4 + j;
            float x  = v[j];
            f0 = fmaf(sM[k],         tanh_from_2x(sW2[k] * x),         f0);
            f1 = fmaf(sM[NPHEN + k], tanh_from_2x(sW2[NFEAT + k] * x), f1);
        }
    }

    // ---- categorical features: register double-buffer, 4 f's per group;
    //      group g+1 loads issued before group g compute -> VMEM never idle.
    #pragma unroll
    for (int g = 0; g < 8; ++g) {
        fx4* cur = (g & 1) ? bufB : bufA;   // static after full unroll
        fx4* nxt = (g & 1) ? bufA : bufB;
        if (g < 7) {
            #pragma unroll
            for (int q = 0; q < 4; ++q) {
                const int f = (g + 1) * 4 + q;
                const fx4* cx = reinterpret_cast<const fx4*>(cbase + (size_t)f * fstride);
                nxt[q * 2 + 0] = __builtin_nontemporal_load(cx);
                nxt[q * 2 + 1] = __builtin_nontemporal_load(cx + 1);
            }
        }
        #pragma unroll
        for (int q = 0; q < 4; ++q) {
            const int f = g * 4 + q;
            const fx4 v0 = cur[q * 2 + 0];
            const fx4 v1 = cur[q * 2 + 1];
            const float* w0 = &sW2[NNUM + f * NCAT];           // 2*W_cat[0][f][:]
            const float* w1 = &sW2[NFEAT + NNUM + f * NCAT];   // 2*W_cat[1][f][:]
            float d0 = 0.0f, d1 = 0.0f;                        // 2*dot
            #pragma unroll
            for (int n = 0; n < 4; ++n) {
                d0 = fmaf(w0[n], v0[n], d0);
                d1 = fmaf(w1[n], v0[n], d1);
            }
            #pragma unroll
            for (int n = 0; n < 4; ++n) {
                d0 = fmaf(w0[4 + n], v1[n], d0);
                d1 = fmaf(w1[4 + n], v1[n], d1);
            }
            f0 = fmaf(sM[NNUM + f],         tanh_from_2x(d0), f0);
            f1 = fmaf(sM[NPHEN + NNUM + f], tanh_from_2x(d1), f1);
        }
    }

    // ---- stable 2-class softmax, nt stores ----
    float e10 = __expf(f1 - f0);
    float o0  = __builtin_amdgcn_rcpf(1.0f + e10);
    __builtin_nontemporal_store(o0,        out + b);
    __builtin_nontemporal_store(1.0f - o0, out + (size_t)Bn + b);
}

extern "C" void kernel_launch(void* const* d_in, const int* in_sizes, int n_in,
                              void* d_out, int out_size, void* d_ws, size_t ws_size,
                              hipStream_t stream) {
    const float* num_x = (const float*)d_in[0];
    const float* cat_x = (const float*)d_in[1];
    const float* W     = (const float*)d_in[2];
    const float* M     = (const float*)d_in[3];
    float* out = (float*)d_out;

    dim3 grid(Bn / 256), block(256);
    hipLaunchKernelGGL(model_kernel, grid, block, 0, stream,
                       num_x, cat_x, W, M, out);
}

// Round 7
// 69.229 us; speedup vs baseline: 1.3213x; 1.3213x over previous
//
#include <hip/hip_runtime.h>

// Problem constants (from reference)
constexpr int Bn    = 262144;
constexpr int NNUM  = 64;
constexpr int FCAT  = 32;
constexpr int NCAT  = 8;
constexpr int NFEAT = NNUM + FCAT * NCAT;  // 320
constexpr int NPHEN = NNUM + FCAT;         // 96

typedef float fx4 __attribute__((ext_vector_type(4)));

// tanh(x) given a = 2x:  tanh(x) = 1 - 2/(exp(2x)+1)
__device__ __forceinline__ float tanh_from_2x(float a) {
    float e = __expf(a);
    float r = __builtin_amdgcn_rcpf(e + 1.0f);
    return fmaf(-2.0f, r, 1.0f);
}

// Two threads per sample (parity split) -> 8192 waves = 32 waves/CU,
// dense num reads (full 128B line per lane-pair), halved per-wave LDS traffic.
__global__ __launch_bounds__(256, 8) void model_kernel(
    const float* __restrict__ num_x,   // (B, 64)
    const float* __restrict__ cat_x,   // (32, B, 8)
    const float* __restrict__ W,       // (2, 320)
    const float* __restrict__ M,       // (2, 96)
    float* __restrict__ out)           // (2, B)
{
    __shared__ float sW2[2 * NFEAT];   // 2*W: dot feeds exp(2x) directly
    __shared__ float sM[2 * NPHEN];
    const int tid = threadIdx.x;
    for (int i = tid; i < 2 * NFEAT; i += 256) sW2[i] = 2.0f * W[i];
    for (int i = tid; i < 2 * NPHEN; i += 256) sM[i] = M[i];
    __syncthreads();

    const int gt = blockIdx.x * 256 + tid;
    const int b  = gt >> 1;        // sample
    const int p  = gt & 1;         // parity: which half of the features

    float f0 = 0.0f, f1 = 0.0f;

    // ---- numerical features: this thread's 32 feats = 128B contiguous ----
    const int k0 = p * 32;
    const fx4* nx = reinterpret_cast<const fx4*>(num_x + (size_t)b * NNUM + k0);
    #pragma unroll
    for (int i = 0; i < 8; ++i) {
        fx4 v = nx[i];
        #pragma unroll
        for (int j = 0; j < 4; ++j) {
            const int k = k0 + i * 4 + j;   // uniform-per-parity LDS idx (2-way bcast, free)
            float x = v[j];
            f0 = fmaf(sM[k],         tanh_from_2x(sW2[k] * x),         f0);
            f1 = fmaf(sM[NPHEN + k], tanh_from_2x(sW2[NFEAT + k] * x), f1);
        }
    }

    // ---- categorical features: this thread's 16 f's, 32B/lane contiguous ----
    const int fbase = p * 16;
    #pragma unroll 4
    for (int fi = 0; fi < 16; ++fi) {
        const int f = fbase + fi;
        const fx4* cx = reinterpret_cast<const fx4*>(
            cat_x + (size_t)f * (size_t)Bn * NCAT + (size_t)b * NCAT);
        fx4 v0 = cx[0];
        fx4 v1 = cx[1];
        const float* w0 = &sW2[NNUM + f * NCAT];           // 2*W_cat[0][f][:]
        const float* w1 = &sW2[NFEAT + NNUM + f * NCAT];   // 2*W_cat[1][f][:]
        float d0 = 0.0f, d1 = 0.0f;                        // 2*dot
        #pragma unroll
        for (int n = 0; n < 4; ++n) {
            d0 = fmaf(w0[n], v0[n], d0);
            d1 = fmaf(w1[n], v0[n], d1);
        }
        #pragma unroll
        for (int n = 0; n < 4; ++n) {
            d0 = fmaf(w0[4 + n], v1[n], d0);
            d1 = fmaf(w1[4 + n], v1[n], d1);
        }
        f0 = fmaf(sM[NNUM + f],         tanh_from_2x(d0), f0);
        f1 = fmaf(sM[NPHEN + NNUM + f], tanh_from_2x(d1), f1);
    }

    // ---- combine the pair's partials (lane ^ 1) ----
    f0 += __shfl_xor(f0, 1);
    f1 += __shfl_xor(f1, 1);

    // ---- stable 2-class softmax; even lane stores class0, odd class1 ----
    float e10 = __expf(f1 - f0);
    float o0  = __builtin_amdgcn_rcpf(1.0f + e10);
    if (p == 0) out[b] = o0;
    else        out[(size_t)Bn + b] = 1.0f - o0;
}

extern "C" void kernel_launch(void* const* d_in, const int* in_sizes, int n_in,
                              void* d_out, int out_size, void* d_ws, size_t ws_size,
                              hipStream_t stream) {
    const float* num_x = (const float*)d_in[0];
    const float* cat_x = (const float*)d_in[1];
    const float* W     = (const float*)d_in[2];
    const float* M     = (const float*)d_in[3];
    float* out = (float*)d_out;

    dim3 grid(2 * Bn / 256), block(256);
    hipLaunchKernelGGL(model_kernel, grid, block, 0, stream,
                       num_x, cat_x, W, M, out);
}